// Round 18
// baseline (825.092 us; speedup 1.0000x reference)
//
#include <hip/hip_runtime.h>

#define NN    500000
#define NE    16000000
#define NBUCK 245        // ceil(NN/2048); bucket = dst >> 11
#define NWGA  1000
#define CHUNKA4 4000     // (NE/NWGA)/4

typedef int      vint4   __attribute__((ext_vector_type(4)));
typedef float    vfloat2 __attribute__((ext_vector_type(2)));
typedef _Float16 vhalf4  __attribute__((ext_vector_type(4)));
typedef _Float16 vhalf2  __attribute__((ext_vector_type(2)));

// ws layout (4B units): dinv NN | p1 NN | p2h 2NN | p3h NN |
// wgHist NWGA*NBUCK | bktTotal NBUCK | bktStart NBUCK+1 | bucketbuf NE
// total ~75 MB (proven ws >= ~141 MB from R10-R17 path-A runs)

// ---- per-WG histogram over dst>>11 (LDS atomics only) ----
__global__ __launch_bounds__(256) void hist_kernel(const int* __restrict__ dst,
                                                   int* __restrict__ wgHist) {
    __shared__ int hist[NBUCK];
    for (int i = threadIdx.x; i < NBUCK; i += 256) hist[i] = 0;
    __syncthreads();
    const vint4* d4 = (const vint4*)(dst + (size_t)blockIdx.x * CHUNKA4 * 4);
    for (int i = threadIdx.x; i < CHUNKA4; i += 256) {
        vint4 d = __builtin_nontemporal_load(d4 + i);
        atomicAdd(&hist[d.x >> 11], 1);
        atomicAdd(&hist[d.y >> 11], 1);
        atomicAdd(&hist[d.z >> 11], 1);
        atomicAdd(&hist[d.w >> 11], 1);
    }
    __syncthreads();
    int* row = wgHist + (size_t)blockIdx.x * NBUCK;
    for (int i = threadIdx.x; i < NBUCK; i += 256) row[i] = hist[i];
}

// ---- per-bucket exclusive scan across WGs: one block per bucket ----
__global__ __launch_bounds__(256) void scanbins_kernel(int* __restrict__ wgHist,
                                                       int* __restrict__ bktTotal) {
    __shared__ int partials[256];
    int bin = blockIdx.x;
    int t = threadIdx.x;
    int per = (NWGA + 255) / 256;
    int w0 = t * per;
    int w1 = w0 + per; if (w1 > NWGA) w1 = NWGA;
    int s = 0;
    for (int w = w0; w < w1; ++w) s += wgHist[(size_t)w * NBUCK + bin];
    partials[t] = s;
    __syncthreads();
    if (t == 0) {
        int run = 0;
        for (int i = 0; i < 256; ++i) { int tmp = partials[i]; partials[i] = run; run += tmp; }
        bktTotal[bin] = run;
    }
    __syncthreads();
    int off = partials[t];
    for (int w = w0; w < w1; ++w) {
        size_t idx = (size_t)w * NBUCK + bin;
        int v = wgHist[idx];
        wgHist[idx] = off;
        off += v;
    }
}

// ---- exclusive scan over buckets ----
__global__ void scantotal_kernel(const int* __restrict__ bktTotal, int* __restrict__ bktStart) {
    __shared__ int partials[256];
    int t = threadIdx.x;
    int v = (t < NBUCK) ? bktTotal[t] : 0;
    partials[t] = v;
    __syncthreads();
    if (t == 0) {
        int run = 0;
        for (int i = 0; i < 256; ++i) { int tmp = partials[i]; partials[i] = run; run += tmp; }
        bktStart[NBUCK] = run;   // == NE
    }
    __syncthreads();
    if (t < NBUCK) bktStart[t] = partials[t];
}

// ---- scatter into buckets; pack (src<<11)|(dst&2047); normal stores.
//      Frontier: ~1000 WGs x 245 lines x 64B = 16MB < L2 -> no write amp. ----
__global__ __launch_bounds__(256) void reorder_kernel(const int* __restrict__ src,
                                                      const int* __restrict__ dst,
                                                      const int* __restrict__ wgHist,
                                                      const int* __restrict__ bktStart,
                                                      int* __restrict__ bucketbuf) {
    __shared__ int cur[NBUCK];
    const int* row = wgHist + (size_t)blockIdx.x * NBUCK;
    for (int i = threadIdx.x; i < NBUCK; i += 256) cur[i] = bktStart[i] + row[i];
    __syncthreads();
    const vint4* s4 = (const vint4*)(src + (size_t)blockIdx.x * CHUNKA4 * 4);
    const vint4* d4 = (const vint4*)(dst + (size_t)blockIdx.x * CHUNKA4 * 4);
    for (int i = threadIdx.x; i < CHUNKA4; i += 256) {
        vint4 s = __builtin_nontemporal_load(s4 + i);
        vint4 d = __builtin_nontemporal_load(d4 + i);
        int ss[4] = {s.x, s.y, s.z, s.w};
        int dd[4] = {d.x, d.y, d.z, d.w};
#pragma unroll
        for (int k = 0; k < 4; ++k) {
            int pos = atomicAdd(&cur[dd[k] >> 11], 1);
            bucketbuf[pos] = (ss[k] << 11) | (dd[k] & 2047);
        }
    }
}

// ---- counts -> dinv/p1 (no rowStart needed anymore) ----
__global__ __launch_bounds__(1024) void count_kernel(const int* __restrict__ bktStart,
                                                     const int* __restrict__ bucketbuf,
                                                     const float* __restrict__ x,
                                                     float* __restrict__ dinv,
                                                     float* __restrict__ p1) {
    __shared__ int cnt[2048];
    int b = blockIdx.x, t = threadIdx.x;
    for (int k = t; k < 2048; k += 1024) cnt[k] = 0;
    __syncthreads();
    int e0 = bktStart[b], e1 = bktStart[b + 1];
    int i = e0 + t;
    for (; i + 3 * 1024 < e1; i += 4 * 1024) {
        int a = bucketbuf[i];
        int c = bucketbuf[i + 1024];
        int d = bucketbuf[i + 2048];
        int e = bucketbuf[i + 3072];
        atomicAdd(&cnt[a & 2047], 1);
        atomicAdd(&cnt[c & 2047], 1);
        atomicAdd(&cnt[d & 2047], 1);
        atomicAdd(&cnt[e & 2047], 1);
    }
    for (; i < e1; i += 1024)
        atomicAdd(&cnt[bucketbuf[i] & 2047], 1);
    __syncthreads();
    for (int k = t; k < 2048; k += 1024) {
        int node = b * 2048 + k;
        if (node < NN) {
            float di = rsqrtf((float)cnt[k] + 1.0f);
            dinv[node] = di;
            p1[node] = x[node] * di;
        }
    }
}

// ---- layer 1: per-bucket LDS accumulate of p1[src], epilogue -> p2h ----
__global__ __launch_bounds__(1024) void agg1L_kernel(const int* __restrict__ bktStart,
                                                     const int* __restrict__ bucketbuf,
                                                     const float* __restrict__ p1,
                                                     const float* __restrict__ dinv,
                                                     const float* __restrict__ W1,
                                                     const float* __restrict__ b1,
                                                     const float* __restrict__ W2,
                                                     vhalf4* __restrict__ p2h) {
    __shared__ float acc[2048];
    int b = blockIdx.x, t = threadIdx.x;
    for (int k = t; k < 2048; k += 1024) acc[k] = 0.0f;
    __syncthreads();
    int e0 = bktStart[b], e1 = bktStart[b + 1];
    int i = e0 + t;
    for (; i + 3 * 1024 < e1; i += 4 * 1024) {
        int ea = bucketbuf[i];
        int eb = bucketbuf[i + 1024];
        int ec = bucketbuf[i + 2048];
        int ed = bucketbuf[i + 3072];
        float va = p1[ea >> 11];
        float vb = p1[eb >> 11];
        float vc = p1[ec >> 11];
        float vd = p1[ed >> 11];
        atomicAdd(&acc[ea & 2047], va);
        atomicAdd(&acc[eb & 2047], vb);
        atomicAdd(&acc[ec & 2047], vc);
        atomicAdd(&acc[ed & 2047], vd);
    }
    for (; i < e1; i += 1024) {
        int e = bucketbuf[i];
        atomicAdd(&acc[e & 2047], p1[e >> 11]);
    }
    __syncthreads();
    for (int k = t; k < 2048; k += 1024) {
        int node = b * 2048 + k;
        if (node < NN) {
            float di = dinv[node];
            float tt = di * (acc[k] + p1[node]);   // norm-agg + self-loop
            float h1[4];
#pragma unroll
            for (int f = 0; f < 4; ++f) h1[f] = tanhf(tt * W1[f] + b1[f]);
            vhalf4 g;
            g.x = (_Float16)(di * (h1[0]*W2[0] + h1[1]*W2[4] + h1[2]*W2[8]  + h1[3]*W2[12]));
            g.y = (_Float16)(di * (h1[0]*W2[1] + h1[1]*W2[5] + h1[2]*W2[9]  + h1[3]*W2[13]));
            g.z = (_Float16)(di * (h1[0]*W2[2] + h1[1]*W2[6] + h1[2]*W2[10] + h1[3]*W2[14]));
            g.w = (_Float16)(di * (h1[0]*W2[3] + h1[1]*W2[7] + h1[2]*W2[11] + h1[3]*W2[15]));
            p2h[node] = g;
        }
    }
}

// ---- layer 2: per-bucket LDS accumulate of p2h[src] (f16x4, 4MB = XCD L2),
//      acc[f*2048+loc] for ~2-way bank spread; epilogue -> p3h ----
__global__ __launch_bounds__(1024) void agg2L_kernel(const int* __restrict__ bktStart,
                                                     const int* __restrict__ bucketbuf,
                                                     const vhalf4* __restrict__ p2h,
                                                     const float* __restrict__ dinv,
                                                     const float* __restrict__ b2,
                                                     const float* __restrict__ W3,
                                                     vhalf2* __restrict__ p3h) {
    __shared__ float acc[4 * 2048];
    int b = blockIdx.x, t = threadIdx.x;
    for (int k = t; k < 4 * 2048; k += 1024) acc[k] = 0.0f;
    __syncthreads();
    int e0 = bktStart[b], e1 = bktStart[b + 1];
    int i = e0 + t;
    for (; i + 1024 < e1; i += 2 * 1024) {
        int ea = bucketbuf[i];
        int eb = bucketbuf[i + 1024];
        vhalf4 qa = p2h[ea >> 11];
        vhalf4 qb = p2h[eb >> 11];
        int la = ea & 2047, lb = eb & 2047;
        atomicAdd(&acc[0 * 2048 + la], (float)qa.x);
        atomicAdd(&acc[1 * 2048 + la], (float)qa.y);
        atomicAdd(&acc[2 * 2048 + la], (float)qa.z);
        atomicAdd(&acc[3 * 2048 + la], (float)qa.w);
        atomicAdd(&acc[0 * 2048 + lb], (float)qb.x);
        atomicAdd(&acc[1 * 2048 + lb], (float)qb.y);
        atomicAdd(&acc[2 * 2048 + lb], (float)qb.z);
        atomicAdd(&acc[3 * 2048 + lb], (float)qb.w);
    }
    for (; i < e1; i += 1024) {
        int e = bucketbuf[i];
        vhalf4 q = p2h[e >> 11];
        int loc = e & 2047;
        atomicAdd(&acc[0 * 2048 + loc], (float)q.x);
        atomicAdd(&acc[1 * 2048 + loc], (float)q.y);
        atomicAdd(&acc[2 * 2048 + loc], (float)q.z);
        atomicAdd(&acc[3 * 2048 + loc], (float)q.w);
    }
    __syncthreads();
    for (int k = t; k < 2048; k += 1024) {
        int node = b * 2048 + k;
        if (node < NN) {
            float di = dinv[node];
            vhalf4 pw = p2h[node];
            float h2[4];
            h2[0] = tanhf(di * (acc[0 * 2048 + k] + (float)pw.x) + b2[0]);
            h2[1] = tanhf(di * (acc[1 * 2048 + k] + (float)pw.y) + b2[1]);
            h2[2] = tanhf(di * (acc[2 * 2048 + k] + (float)pw.z) + b2[2]);
            h2[3] = tanhf(di * (acc[3 * 2048 + k] + (float)pw.w) + b2[3]);
            vhalf2 o;
            o.x = (_Float16)(di * (h2[0]*W3[0] + h2[1]*W3[2] + h2[2]*W3[4] + h2[3]*W3[6]));
            o.y = (_Float16)(di * (h2[0]*W3[1] + h2[1]*W3[3] + h2[2]*W3[5] + h2[3]*W3[7]));
            p3h[node] = o;
        }
    }
}

// ---- layer 3: per-bucket LDS accumulate of p3h[src] (f16x2, 2MB), -> out ----
__global__ __launch_bounds__(1024) void agg3L_kernel(const int* __restrict__ bktStart,
                                                     const int* __restrict__ bucketbuf,
                                                     const vhalf2* __restrict__ p3h,
                                                     const float* __restrict__ dinv,
                                                     const float* __restrict__ b3,
                                                     const float* __restrict__ Wc,
                                                     const float* __restrict__ bc,
                                                     float* __restrict__ out) {
    __shared__ float acc[2 * 2048];
    int b = blockIdx.x, t = threadIdx.x;
    for (int k = t; k < 2 * 2048; k += 1024) acc[k] = 0.0f;
    __syncthreads();
    int e0 = bktStart[b], e1 = bktStart[b + 1];
    int i = e0 + t;
    for (; i + 3 * 1024 < e1; i += 4 * 1024) {
        int ea = bucketbuf[i];
        int eb = bucketbuf[i + 1024];
        int ec = bucketbuf[i + 2048];
        int ed = bucketbuf[i + 3072];
        vhalf2 qa = p3h[ea >> 11];
        vhalf2 qb = p3h[eb >> 11];
        vhalf2 qc = p3h[ec >> 11];
        vhalf2 qd = p3h[ed >> 11];
        int la = ea & 2047, lb = eb & 2047, lc = ec & 2047, ld = ed & 2047;
        atomicAdd(&acc[0 * 2048 + la], (float)qa.x);
        atomicAdd(&acc[1 * 2048 + la], (float)qa.y);
        atomicAdd(&acc[0 * 2048 + lb], (float)qb.x);
        atomicAdd(&acc[1 * 2048 + lb], (float)qb.y);
        atomicAdd(&acc[0 * 2048 + lc], (float)qc.x);
        atomicAdd(&acc[1 * 2048 + lc], (float)qc.y);
        atomicAdd(&acc[0 * 2048 + ld], (float)qd.x);
        atomicAdd(&acc[1 * 2048 + ld], (float)qd.y);
    }
    for (; i < e1; i += 1024) {
        int e = bucketbuf[i];
        vhalf2 q = p3h[e >> 11];
        int loc = e & 2047;
        atomicAdd(&acc[0 * 2048 + loc], (float)q.x);
        atomicAdd(&acc[1 * 2048 + loc], (float)q.y);
    }
    __syncthreads();
    for (int k = t; k < 2048; k += 1024) {
        int node = b * 2048 + k;
        if (node < NN) {
            float di = dinv[node];
            vhalf2 pw = p3h[node];
            float h0 = tanhf(di * (acc[0 * 2048 + k] + (float)pw.x) + b3[0]);
            float h1 = tanhf(di * (acc[1 * 2048 + k] + (float)pw.y) + b3[1]);
            __builtin_nontemporal_store(h0 * Wc[0] + h1 * Wc[1] + bc[0], out + node);
            vfloat2 hh; hh.x = h0; hh.y = h1;
            __builtin_nontemporal_store(hh, (vfloat2*)(out + NN) + node);
        }
    }
}

// ============================ launch ============================

extern "C" void kernel_launch(void* const* d_in, const int* in_sizes, int n_in,
                              void* d_out, int out_size, void* d_ws, size_t ws_size,
                              hipStream_t stream) {
    const float* x   = (const float*)d_in[0];
    const int*   ei  = (const int*)d_in[1];
    const float* W1  = (const float*)d_in[2];
    const float* b1  = (const float*)d_in[3];
    const float* W2  = (const float*)d_in[4];
    const float* b2  = (const float*)d_in[5];
    const float* W3  = (const float*)d_in[6];
    const float* b3  = (const float*)d_in[7];
    const float* Wc  = (const float*)d_in[8];
    const float* bc  = (const float*)d_in[9];
    float* out = (float*)d_out;
    float* ws  = (float*)d_ws;

    const int* src = ei;
    const int* dst = ei + NE;

    float*  dinv      = ws;
    float*  p1        = ws + (size_t)NN;
    vhalf4* p2h       = (vhalf4*)(ws + 2ull * NN);
    vhalf2* p3h       = (vhalf2*)(ws + 4ull * NN);
    int*    wgHist    = (int*)(ws + 5ull * NN);
    int*    bktTotal  = wgHist + (size_t)NWGA * NBUCK;
    int*    bktStart  = bktTotal + NBUCK;
    int*    bucketbuf = bktStart + NBUCK + 1;

    hipLaunchKernelGGL(hist_kernel, dim3(NWGA), dim3(256), 0, stream, dst, wgHist);
    hipLaunchKernelGGL(scanbins_kernel, dim3(NBUCK), dim3(256), 0, stream,
                       wgHist, bktTotal);
    hipLaunchKernelGGL(scantotal_kernel, dim3(1), dim3(256), 0, stream,
                       bktTotal, bktStart);
    hipLaunchKernelGGL(reorder_kernel, dim3(NWGA), dim3(256), 0, stream,
                       src, dst, wgHist, bktStart, bucketbuf);
    hipLaunchKernelGGL(count_kernel, dim3(NBUCK), dim3(1024), 0, stream,
                       bktStart, bucketbuf, x, dinv, p1);
    hipLaunchKernelGGL(agg1L_kernel, dim3(NBUCK), dim3(1024), 0, stream,
                       bktStart, bucketbuf, p1, dinv, W1, b1, W2, p2h);
    hipLaunchKernelGGL(agg2L_kernel, dim3(NBUCK), dim3(1024), 0, stream,
                       bktStart, bucketbuf, p2h, dinv, b2, W3, p3h);
    hipLaunchKernelGGL(agg3L_kernel, dim3(NBUCK), dim3(1024), 0, stream,
                       bktStart, bucketbuf, p3h, dinv, b3, Wc, bc, out);
}

// Round 19
// 675.983 us; speedup vs baseline: 1.2206x; 1.2206x over previous
//
#include <hip/hip_runtime.h>

#define NN    500000
#define NE    16000000
#define NBUCK 245        // ceil(NN/2048); bucket = dst >> 11
#define NWGA  1000
#define CHUNKA4 4000     // (NE/NWGA)/4

typedef int      vint4   __attribute__((ext_vector_type(4)));
typedef float    vfloat4 __attribute__((ext_vector_type(4)));
typedef float    vfloat2 __attribute__((ext_vector_type(2)));
typedef _Float16 vhalf4  __attribute__((ext_vector_type(4)));
typedef _Float16 vhalf2  __attribute__((ext_vector_type(2)));

// ws layout (4B units): dinv NN | p1 NN | p2h 2NN | p3h NN | rowStart NN+1 |
// wgHist NWGA*NBUCK | bktTotal NBUCK | bktStart NBUCK+1 | bucketbuf NE | edgebuf NE
// total ~140 MB (path A ran R10-R17 -> ws_size >= this)

// ---- per-WG histogram over dst>>11 (LDS atomics only) ----
__global__ __launch_bounds__(512) void hist_kernel(const int* __restrict__ dst,
                                                   int* __restrict__ wgHist) {
    __shared__ int hist[NBUCK];
    for (int i = threadIdx.x; i < NBUCK; i += 512) hist[i] = 0;
    __syncthreads();
    const vint4* d4 = (const vint4*)(dst + (size_t)blockIdx.x * CHUNKA4 * 4);
    for (int i = threadIdx.x; i < CHUNKA4; i += 512) {
        vint4 d = __builtin_nontemporal_load(d4 + i);
        atomicAdd(&hist[d.x >> 11], 1);
        atomicAdd(&hist[d.y >> 11], 1);
        atomicAdd(&hist[d.z >> 11], 1);
        atomicAdd(&hist[d.w >> 11], 1);
    }
    __syncthreads();
    int* row = wgHist + (size_t)blockIdx.x * NBUCK;
    for (int i = threadIdx.x; i < NBUCK; i += 512) row[i] = hist[i];
}

// ---- per-bucket exclusive scan across WGs: one block per bucket ----
__global__ __launch_bounds__(256) void scanbins_kernel(int* __restrict__ wgHist,
                                                       int* __restrict__ bktTotal) {
    __shared__ int partials[256];
    int bin = blockIdx.x;
    int t = threadIdx.x;
    int per = (NWGA + 255) / 256;
    int w0 = t * per;
    int w1 = w0 + per; if (w1 > NWGA) w1 = NWGA;
    int s = 0;
    for (int w = w0; w < w1; ++w) s += wgHist[(size_t)w * NBUCK + bin];
    partials[t] = s;
    __syncthreads();
    if (t == 0) {
        int run = 0;
        for (int i = 0; i < 256; ++i) { int tmp = partials[i]; partials[i] = run; run += tmp; }
        bktTotal[bin] = run;
    }
    __syncthreads();
    int off = partials[t];
    for (int w = w0; w < w1; ++w) {
        size_t idx = (size_t)w * NBUCK + bin;
        int v = wgHist[idx];
        wgHist[idx] = off;
        off += v;
    }
}

// ---- exclusive scan over buckets ----
__global__ void scantotal_kernel(const int* __restrict__ bktTotal, int* __restrict__ bktStart) {
    __shared__ int partials[256];
    int t = threadIdx.x;
    int v = (t < NBUCK) ? bktTotal[t] : 0;
    partials[t] = v;
    __syncthreads();
    if (t == 0) {
        int run = 0;
        for (int i = 0; i < 256; ++i) { int tmp = partials[i]; partials[i] = run; run += tmp; }
        bktStart[NBUCK] = run;   // == NE
    }
    __syncthreads();
    if (t < NBUCK) bktStart[t] = partials[t];
}

// ---- scatter into buckets; pack (src<<11)|(dst&2047); normal stores.
//      Frontier: ~resident WGs x 245 lines x 64B < L2 -> no write amp. ----
__global__ __launch_bounds__(512) void reorder_kernel(const int* __restrict__ src,
                                                      const int* __restrict__ dst,
                                                      const int* __restrict__ wgHist,
                                                      const int* __restrict__ bktStart,
                                                      int* __restrict__ bucketbuf) {
    __shared__ int cur[NBUCK];
    const int* row = wgHist + (size_t)blockIdx.x * NBUCK;
    for (int i = threadIdx.x; i < NBUCK; i += 512) cur[i] = bktStart[i] + row[i];
    __syncthreads();
    const vint4* s4 = (const vint4*)(src + (size_t)blockIdx.x * CHUNKA4 * 4);
    const vint4* d4 = (const vint4*)(dst + (size_t)blockIdx.x * CHUNKA4 * 4);
    for (int i = threadIdx.x; i < CHUNKA4; i += 512) {
        vint4 s = __builtin_nontemporal_load(s4 + i);
        vint4 d = __builtin_nontemporal_load(d4 + i);
        int ss[4] = {s.x, s.y, s.z, s.w};
        int dd[4] = {d.x, d.y, d.z, d.w};
#pragma unroll
        for (int k = 0; k < 4; ++k) {
            int pos = atomicAdd(&cur[dd[k] >> 11], 1);
            bucketbuf[pos] = (ss[k] << 11) | (dd[k] & 2047);
        }
    }
}

// ---- fused pass 2: count + prefix + dinv/p1/rowStart + scatter + agg1 +
//      layer-1 epilogue, one kernel (saves count_kernel's 64MB re-read). ----
__global__ __launch_bounds__(1024) void csr3_kernel(const int* __restrict__ bktStart,
                                                    const int* __restrict__ bucketbuf,
                                                    const float* __restrict__ x,
                                                    float* __restrict__ dinv,
                                                    float* __restrict__ p1,
                                                    int* __restrict__ rowStart,
                                                    const float* __restrict__ W1,
                                                    const float* __restrict__ b1,
                                                    const float* __restrict__ W2,
                                                    int* __restrict__ edgebuf,
                                                    vhalf4* __restrict__ p2h) {
    __shared__ int   cnt[2048];      // counts -> absolute cursors (in place)
    __shared__ float acc[2048];
    __shared__ int   partials[1024];
    int b = blockIdx.x, t = threadIdx.x;
    for (int k = t; k < 2048; k += 1024) { cnt[k] = 0; acc[k] = 0.0f; }
    __syncthreads();
    int e0 = bktStart[b], e1 = bktStart[b + 1];
    // phase 1: per-node counts
    int i = e0 + t;
    for (; i + 3 * 1024 < e1; i += 4 * 1024) {
        int a = bucketbuf[i];
        int c = bucketbuf[i + 1024];
        int d = bucketbuf[i + 2048];
        int e = bucketbuf[i + 3072];
        atomicAdd(&cnt[a & 2047], 1);
        atomicAdd(&cnt[c & 2047], 1);
        atomicAdd(&cnt[d & 2047], 1);
        atomicAdd(&cnt[e & 2047], 1);
    }
    for (; i < e1; i += 1024)
        atomicAdd(&cnt[bucketbuf[i] & 2047], 1);
    __syncthreads();
    // prefix over 2048 (2 per thread)
    int k0 = t * 2;
    int c0 = cnt[k0], c1 = cnt[k0 + 1];
    partials[t] = c0 + c1;
    __syncthreads();
    if (t == 0) {
        int run = 0;
        for (int k = 0; k < 1024; ++k) { int tmp = partials[k]; partials[k] = run; run += tmp; }
    }
    __syncthreads();
    int off = partials[t];
    // dinv/p1/rowStart + cursors (cnt in place)
    {
        int node = b * 2048 + k0;
        if (node < NN) {
            rowStart[node] = e0 + off;
            float di = rsqrtf((float)c0 + 1.0f);
            dinv[node] = di;
            p1[node] = x[node] * di;
        }
        int cur0 = e0 + off; off += c0;
        int node1 = node + 1;
        if (node1 < NN) {
            rowStart[node1] = e0 + off;
            float di = rsqrtf((float)c1 + 1.0f);
            dinv[node1] = di;
            p1[node1] = x[node1] * di;
        }
        int cur1 = e0 + off; off += c1;
        cnt[k0] = cur0;
        cnt[k0 + 1] = cur1;
    }
    if (b == NBUCK - 1 && t == 0) rowStart[NN] = e1;
    __syncthreads();
    // phase 2: scatter + agg1 accumulate (p1 is only needed for THIS bucket's
    // sources? No - sources are cross-bucket; but p1 covers all nodes because
    // every bucket's phase-1 ran... FALSE for cross-bucket srcs whose bucket
    // hasn't run. p1[src] here would race. So gather from x*dinv is NOT safe;
    // instead accumulate raw p1 AFTER it's globally ready? We keep correctness:
    // agg1 needs p1[src] for arbitrary src -> must NOT read p1 here unless
    // globally complete. Solution: accumulate using x[src]*rsqrt(deg[src])?
    // deg[src] unknown here. => keep agg1 accumulation but source values from
    // p1 computed in THIS kernel only if same bucket. Not general.
    // => Fall back to: scatter only here; p1 gathering done by re-reading
    //    edgebuf? That reintroduces agg1. Instead: note the harness runs
    //    kernels in sequence; csr3 grid is NOT globally synced. We therefore
    //    accumulate x[src] and dinv[src] CANNOT be used.
    // RESOLUTION (correct): accumulate sum of x[src]*dinv[src] is required;
    // dinv depends only on counts which are LOCAL per destination bucket for
    // its own nodes - dinv[src] belongs to src's bucket. Not available.
    // => We precompute dinv/p1 in a SEPARATE earlier pass? That's count_kernel
    // again. To keep this kernel correct WITHOUT count_kernel, we accumulate
    // edge list only and let agg1 read p1 afterwards: but p1 IS complete after
    // this kernel (all buckets wrote their nodes) -> separate agg1 pass needed.
    // => We instead fuse agg1 into agg2's kernel? No. SAFETY: do scatter only,
    // and fused agg1 epilogue moved to a tiny follow-up kernel agg1_kernel
    // (CSR register gather, ~90us) as in path B. See launch: agg1 re-added.
    for (i = e0 + t; i + 3 * 1024 < e1; i += 4 * 1024) {
        int ea = bucketbuf[i];
        int eb = bucketbuf[i + 1024];
        int ec = bucketbuf[i + 2048];
        int ed = bucketbuf[i + 3072];
        int la = ea & 2047, sa = ea >> 11;
        int lb = eb & 2047, sb = eb >> 11;
        int lc = ec & 2047, sc = ec >> 11;
        int ld = ed & 2047, sd = ed >> 11;
        int pa = atomicAdd(&cnt[la], 1);
        int pb = atomicAdd(&cnt[lb], 1);
        int pc = atomicAdd(&cnt[lc], 1);
        int pd = atomicAdd(&cnt[ld], 1);
        edgebuf[pa] = sa;
        edgebuf[pb] = sb;
        edgebuf[pc] = sc;
        edgebuf[pd] = sd;
    }
    for (; i < e1; i += 1024) {
        int e = bucketbuf[i];
        int pos = atomicAdd(&cnt[e & 2047], 1);
        edgebuf[pos] = e >> 11;
    }
}

// ---- layer 1: per-node register gather of p1 (f32), ILP-8 -> p2h (f16x4) ----
__global__ __launch_bounds__(256) void agg1_kernel(const int* __restrict__ rowStart,
                                                   const int* __restrict__ edgebuf,
                                                   const float* __restrict__ p1,
                                                   const float* __restrict__ dinv,
                                                   const float* __restrict__ W1,
                                                   const float* __restrict__ b1,
                                                   const float* __restrict__ W2,
                                                   vhalf4* __restrict__ p2h) {
    int node = blockIdx.x * blockDim.x + threadIdx.x;
    if (node >= NN) return;
    int r0 = rowStart[node], r1 = rowStart[node + 1];
    float s0 = 0.f, s1 = 0.f, s2 = 0.f, s3 = 0.f;
    float s4 = 0.f, s5 = 0.f, s6 = 0.f, s7 = 0.f;
    int k = r0;
    for (; k + 8 <= r1; k += 8) {
        int a = edgebuf[k],     b = edgebuf[k + 1];
        int c = edgebuf[k + 2], d = edgebuf[k + 3];
        int e = edgebuf[k + 4], f = edgebuf[k + 5];
        int g = edgebuf[k + 6], h = edgebuf[k + 7];
        s0 += p1[a]; s1 += p1[b]; s2 += p1[c]; s3 += p1[d];
        s4 += p1[e]; s5 += p1[f]; s6 += p1[g]; s7 += p1[h];
    }
    for (; k < r1; ++k) s0 += p1[edgebuf[k]];
    float acc = ((s0 + s1) + (s2 + s3)) + ((s4 + s5) + (s6 + s7));
    float di = dinv[node];
    float t = di * (acc + p1[node]);   // norm-agg + self-loop
    float h1[4];
#pragma unroll
    for (int f2 = 0; f2 < 4; ++f2) h1[f2] = tanhf(t * W1[f2] + b1[f2]);
    vhalf4 g;
    g.x = (_Float16)(di * (h1[0]*W2[0] + h1[1]*W2[4] + h1[2]*W2[8]  + h1[3]*W2[12]));
    g.y = (_Float16)(di * (h1[0]*W2[1] + h1[1]*W2[5] + h1[2]*W2[9]  + h1[3]*W2[13]));
    g.z = (_Float16)(di * (h1[0]*W2[2] + h1[1]*W2[6] + h1[2]*W2[10] + h1[3]*W2[14]));
    g.w = (_Float16)(di * (h1[0]*W2[3] + h1[1]*W2[7] + h1[2]*W2[11] + h1[3]*W2[15]));
    p2h[node] = g;
}

// ---- layer 2: per-node register gather of p2h (f16x4, 4MB table), ILP-8 ----
__global__ __launch_bounds__(256) void agg2_kernel(const int* __restrict__ rowStart,
                                                   const int* __restrict__ edgebuf,
                                                   const vhalf4* __restrict__ p2h,
                                                   const float* __restrict__ dinv,
                                                   const float* __restrict__ b2,
                                                   const float* __restrict__ W3,
                                                   vhalf2* __restrict__ p3h) {
    int node = blockIdx.x * blockDim.x + threadIdx.x;
    if (node >= NN) return;
    int r0 = rowStart[node], r1 = rowStart[node + 1];
    vfloat4 sA = {0.f, 0.f, 0.f, 0.f};
    vfloat4 sB = {0.f, 0.f, 0.f, 0.f};
    vfloat4 sC = {0.f, 0.f, 0.f, 0.f};
    vfloat4 sD = {0.f, 0.f, 0.f, 0.f};
    int k = r0;
    for (; k + 8 <= r1; k += 8) {
        int a = edgebuf[k],     b = edgebuf[k + 1];
        int c = edgebuf[k + 2], d = edgebuf[k + 3];
        int e = edgebuf[k + 4], f = edgebuf[k + 5];
        int g = edgebuf[k + 6], h = edgebuf[k + 7];
        vhalf4 qa = p2h[a], qb = p2h[b], qc = p2h[c], qd = p2h[d];
        vhalf4 qe = p2h[e], qf = p2h[f], qg = p2h[g], qh = p2h[h];
        sA.x += (float)qa.x + (float)qb.x; sB.x += (float)qc.x + (float)qd.x;
        sA.y += (float)qa.y + (float)qb.y; sB.y += (float)qc.y + (float)qd.y;
        sA.z += (float)qa.z + (float)qb.z; sB.z += (float)qc.z + (float)qd.z;
        sA.w += (float)qa.w + (float)qb.w; sB.w += (float)qc.w + (float)qd.w;
        sC.x += (float)qe.x + (float)qf.x; sD.x += (float)qg.x + (float)qh.x;
        sC.y += (float)qe.y + (float)qf.y; sD.y += (float)qg.y + (float)qh.y;
        sC.z += (float)qe.z + (float)qf.z; sD.z += (float)qg.z + (float)qh.z;
        sC.w += (float)qe.w + (float)qf.w; sD.w += (float)qg.w + (float)qh.w;
    }
    for (; k < r1; ++k) {
        vhalf4 q = p2h[edgebuf[k]];
        sA.x += (float)q.x; sA.y += (float)q.y; sA.z += (float)q.z; sA.w += (float)q.w;
    }
    float di = dinv[node];
    vhalf4 pw = p2h[node];
    float h2[4];
    h2[0] = tanhf(di * (sA.x + sB.x + sC.x + sD.x + (float)pw.x) + b2[0]);
    h2[1] = tanhf(di * (sA.y + sB.y + sC.y + sD.y + (float)pw.y) + b2[1]);
    h2[2] = tanhf(di * (sA.z + sB.z + sC.z + sD.z + (float)pw.z) + b2[2]);
    h2[3] = tanhf(di * (sA.w + sB.w + sC.w + sD.w + (float)pw.w) + b2[3]);
    vhalf2 o;
    o.x = (_Float16)(di * (h2[0]*W3[0] + h2[1]*W3[2] + h2[2]*W3[4] + h2[3]*W3[6]));
    o.y = (_Float16)(di * (h2[0]*W3[1] + h2[1]*W3[3] + h2[2]*W3[5] + h2[3]*W3[7]));
    p3h[node] = o;
}

// ---- layer 3: per-node register gather of p3h (f16x2, 2MB table), ILP-8 ----
__global__ __launch_bounds__(256) void agg3_kernel(const int* __restrict__ rowStart,
                                                   const int* __restrict__ edgebuf,
                                                   const vhalf2* __restrict__ p3h,
                                                   const float* __restrict__ dinv,
                                                   const float* __restrict__ b3,
                                                   const float* __restrict__ Wc,
                                                   const float* __restrict__ bc,
                                                   float* __restrict__ out) {
    int node = blockIdx.x * blockDim.x + threadIdx.x;
    if (node >= NN) return;
    int r0 = rowStart[node], r1 = rowStart[node + 1];
    float ax = 0.f, ay = 0.f, bx = 0.f, by = 0.f;
    float cx = 0.f, cy = 0.f, dx = 0.f, dy = 0.f;
    int k = r0;
    for (; k + 8 <= r1; k += 8) {
        int a = edgebuf[k],     b = edgebuf[k + 1];
        int c = edgebuf[k + 2], d = edgebuf[k + 3];
        int e = edgebuf[k + 4], f = edgebuf[k + 5];
        int g = edgebuf[k + 6], h = edgebuf[k + 7];
        vhalf2 qa = p3h[a], qb = p3h[b], qc = p3h[c], qd = p3h[d];
        vhalf2 qe = p3h[e], qf = p3h[f], qg = p3h[g], qh = p3h[h];
        ax += (float)qa.x + (float)qb.x; bx += (float)qc.x + (float)qd.x;
        ay += (float)qa.y + (float)qb.y; by += (float)qc.y + (float)qd.y;
        cx += (float)qe.x + (float)qf.x; dx += (float)qg.x + (float)qh.x;
        cy += (float)qe.y + (float)qf.y; dy += (float)qg.y + (float)qh.y;
    }
    for (; k < r1; ++k) {
        vhalf2 q = p3h[edgebuf[k]];
        ax += (float)q.x; ay += (float)q.y;
    }
    float di = dinv[node];
    vhalf2 pw = p3h[node];
    float h0 = tanhf(di * (ax + bx + cx + dx + (float)pw.x) + b3[0]);
    float h1 = tanhf(di * (ay + by + cy + dy + (float)pw.y) + b3[1]);
    __builtin_nontemporal_store(h0 * Wc[0] + h1 * Wc[1] + bc[0], out + node);
    vfloat2 hh; hh.x = h0; hh.y = h1;
    __builtin_nontemporal_store(hh, (vfloat2*)(out + NN) + node);
}

// ============================ launch ============================

extern "C" void kernel_launch(void* const* d_in, const int* in_sizes, int n_in,
                              void* d_out, int out_size, void* d_ws, size_t ws_size,
                              hipStream_t stream) {
    const float* x   = (const float*)d_in[0];
    const int*   ei  = (const int*)d_in[1];
    const float* W1  = (const float*)d_in[2];
    const float* b1  = (const float*)d_in[3];
    const float* W2  = (const float*)d_in[4];
    const float* b2  = (const float*)d_in[5];
    const float* W3  = (const float*)d_in[6];
    const float* b3  = (const float*)d_in[7];
    const float* Wc  = (const float*)d_in[8];
    const float* bc  = (const float*)d_in[9];
    float* out = (float*)d_out;
    float* ws  = (float*)d_ws;

    const int* src = ei;
    const int* dst = ei + NE;

    float*  dinv      = ws;
    float*  p1        = ws + (size_t)NN;
    vhalf4* p2h       = (vhalf4*)(ws + 2ull * NN);
    vhalf2* p3h       = (vhalf2*)(ws + 4ull * NN);
    int*    rowStart  = (int*)(ws + 5ull * NN);
    int*    wgHist    = (int*)(ws + 6ull * NN + 1);
    int*    bktTotal  = wgHist + (size_t)NWGA * NBUCK;
    int*    bktStart  = bktTotal + NBUCK;
    int*    bucketbuf = bktStart + NBUCK + 1;
    int*    edgebuf   = bucketbuf + (size_t)NE;

    const int aggGrid = (NN + 255) / 256;            // 1954

    hipLaunchKernelGGL(hist_kernel, dim3(NWGA), dim3(512), 0, stream, dst, wgHist);
    hipLaunchKernelGGL(scanbins_kernel, dim3(NBUCK), dim3(256), 0, stream,
                       wgHist, bktTotal);
    hipLaunchKernelGGL(scantotal_kernel, dim3(1), dim3(256), 0, stream,
                       bktTotal, bktStart);
    hipLaunchKernelGGL(reorder_kernel, dim3(NWGA), dim3(512), 0, stream,
                       src, dst, wgHist, bktStart, bucketbuf);
    hipLaunchKernelGGL(csr3_kernel, dim3(NBUCK), dim3(1024), 0, stream,
                       bktStart, bucketbuf, x, dinv, p1, rowStart, W1, b1, W2,
                       edgebuf, p2h);
    hipLaunchKernelGGL(agg1_kernel, dim3(aggGrid), dim3(256), 0, stream,
                       rowStart, edgebuf, p1, dinv, W1, b1, W2, p2h);
    hipLaunchKernelGGL(agg2_kernel, dim3(aggGrid), dim3(256), 0, stream,
                       rowStart, edgebuf, p2h, dinv, b2, W3, p3h);
    hipLaunchKernelGGL(agg3_kernel, dim3(aggGrid), dim3(256), 0, stream,
                       rowStart, edgebuf, p3h, dinv, b3, Wc, bc, out);
}

// Round 20
// 668.837 us; speedup vs baseline: 1.2336x; 1.0107x over previous
//
#include <hip/hip_runtime.h>

#define NN    500000
#define NE    16000000
#define NBUCK 245        // ceil(NN/2048); bucket = dst >> 11
#define NWGA  2000
#define CHUNKA4 2000     // (NE/NWGA)/4

typedef int      vint4   __attribute__((ext_vector_type(4)));
typedef float    vfloat4 __attribute__((ext_vector_type(4)));
typedef float    vfloat2 __attribute__((ext_vector_type(2)));
typedef _Float16 vhalf4  __attribute__((ext_vector_type(4)));
typedef _Float16 vhalf2  __attribute__((ext_vector_type(2)));

// ws layout (4B units): dinv NN | p1 NN | p2h 2NN | p3h NN | rowStart NN+1 |
// wgHist NWGA*NBUCK | bktTotal NBUCK | bktStart NBUCK+1 | bucketbuf NE | edgebuf NE

// ---- per-WG histogram over dst>>11; 4x replicated sub-hists to cut
//      same-address LDS-atomic serialization (R19 hist ran at 1.4 TB/s) ----
__global__ __launch_bounds__(512) void hist_kernel(const int* __restrict__ dst,
                                                   int* __restrict__ wgHist) {
    __shared__ int hist[4 * 256];
    for (int i = threadIdx.x; i < 4 * 256; i += 512) hist[i] = 0;
    __syncthreads();
    int rep = (threadIdx.x & 3) * 256;
    const vint4* d4 = (const vint4*)(dst + (size_t)blockIdx.x * CHUNKA4 * 4);
    for (int i = threadIdx.x; i < CHUNKA4; i += 512) {
        vint4 d = __builtin_nontemporal_load(d4 + i);
        atomicAdd(&hist[rep + (d.x >> 11)], 1);
        atomicAdd(&hist[rep + (d.y >> 11)], 1);
        atomicAdd(&hist[rep + (d.z >> 11)], 1);
        atomicAdd(&hist[rep + (d.w >> 11)], 1);
    }
    __syncthreads();
    int* row = wgHist + (size_t)blockIdx.x * NBUCK;
    for (int i = threadIdx.x; i < NBUCK; i += 512)
        row[i] = hist[i] + hist[256 + i] + hist[512 + i] + hist[768 + i];
}

// ---- per-bucket exclusive scan across WGs: one block per bucket ----
__global__ __launch_bounds__(256) void scanbins_kernel(int* __restrict__ wgHist,
                                                       int* __restrict__ bktTotal) {
    __shared__ int partials[256];
    int bin = blockIdx.x;
    int t = threadIdx.x;
    int per = (NWGA + 255) / 256;
    int w0 = t * per;
    int w1 = w0 + per; if (w1 > NWGA) w1 = NWGA;
    int s = 0;
    for (int w = w0; w < w1; ++w) s += wgHist[(size_t)w * NBUCK + bin];
    partials[t] = s;
    __syncthreads();
    if (t == 0) {
        int run = 0;
        for (int i = 0; i < 256; ++i) { int tmp = partials[i]; partials[i] = run; run += tmp; }
        bktTotal[bin] = run;
    }
    __syncthreads();
    int off = partials[t];
    for (int w = w0; w < w1; ++w) {
        size_t idx = (size_t)w * NBUCK + bin;
        int v = wgHist[idx];
        wgHist[idx] = off;
        off += v;
    }
}

// ---- exclusive scan over buckets ----
__global__ void scantotal_kernel(const int* __restrict__ bktTotal, int* __restrict__ bktStart) {
    __shared__ int partials[256];
    int t = threadIdx.x;
    int v = (t < NBUCK) ? bktTotal[t] : 0;
    partials[t] = v;
    __syncthreads();
    if (t == 0) {
        int run = 0;
        for (int i = 0; i < 256; ++i) { int tmp = partials[i]; partials[i] = run; run += tmp; }
        bktStart[NBUCK] = run;   // == NE
    }
    __syncthreads();
    if (t < NBUCK) bktStart[t] = partials[t];
}

// ---- scatter into buckets; pack (src<<11)|(dst&2047); normal stores.
//      Frontier: resident WGs x 245 lines x 64B ~= 16MB < L2 -> no write amp. ----
__global__ __launch_bounds__(512) void reorder_kernel(const int* __restrict__ src,
                                                      const int* __restrict__ dst,
                                                      const int* __restrict__ wgHist,
                                                      const int* __restrict__ bktStart,
                                                      int* __restrict__ bucketbuf) {
    __shared__ int cur[NBUCK];
    const int* row = wgHist + (size_t)blockIdx.x * NBUCK;
    for (int i = threadIdx.x; i < NBUCK; i += 512) cur[i] = bktStart[i] + row[i];
    __syncthreads();
    const vint4* s4 = (const vint4*)(src + (size_t)blockIdx.x * CHUNKA4 * 4);
    const vint4* d4 = (const vint4*)(dst + (size_t)blockIdx.x * CHUNKA4 * 4);
    for (int i = threadIdx.x; i < CHUNKA4; i += 512) {
        vint4 s = __builtin_nontemporal_load(s4 + i);
        vint4 d = __builtin_nontemporal_load(d4 + i);
        int ss[4] = {s.x, s.y, s.z, s.w};
        int dd[4] = {d.x, d.y, d.z, d.w};
#pragma unroll
        for (int k = 0; k < 4; ++k) {
            int pos = atomicAdd(&cur[dd[k] >> 11], 1);
            bucketbuf[pos] = (ss[k] << 11) | (dd[k] & 2047);
        }
    }
}

// ---- fused pass 2: count + prefix + dinv/p1/rowStart + scatter ----
__global__ __launch_bounds__(1024) void csr3_kernel(const int* __restrict__ bktStart,
                                                    const int* __restrict__ bucketbuf,
                                                    const float* __restrict__ x,
                                                    float* __restrict__ dinv,
                                                    float* __restrict__ p1,
                                                    int* __restrict__ rowStart,
                                                    int* __restrict__ edgebuf) {
    __shared__ int cnt[2048];      // counts -> absolute cursors (in place)
    __shared__ int partials[1024];
    int b = blockIdx.x, t = threadIdx.x;
    for (int k = t; k < 2048; k += 1024) cnt[k] = 0;
    __syncthreads();
    int e0 = bktStart[b], e1 = bktStart[b + 1];
    // phase 1: per-node counts
    int i = e0 + t;
    for (; i + 3 * 1024 < e1; i += 4 * 1024) {
        int a = bucketbuf[i];
        int c = bucketbuf[i + 1024];
        int d = bucketbuf[i + 2048];
        int e = bucketbuf[i + 3072];
        atomicAdd(&cnt[a & 2047], 1);
        atomicAdd(&cnt[c & 2047], 1);
        atomicAdd(&cnt[d & 2047], 1);
        atomicAdd(&cnt[e & 2047], 1);
    }
    for (; i < e1; i += 1024)
        atomicAdd(&cnt[bucketbuf[i] & 2047], 1);
    __syncthreads();
    // prefix over 2048 (2 per thread)
    int k0 = t * 2;
    int c0 = cnt[k0], c1 = cnt[k0 + 1];
    partials[t] = c0 + c1;
    __syncthreads();
    if (t == 0) {
        int run = 0;
        for (int k = 0; k < 1024; ++k) { int tmp = partials[k]; partials[k] = run; run += tmp; }
    }
    __syncthreads();
    int off = partials[t];
    {
        int node = b * 2048 + k0;
        if (node < NN) {
            rowStart[node] = e0 + off;
            float di = rsqrtf((float)c0 + 1.0f);
            dinv[node] = di;
            p1[node] = x[node] * di;
        }
        int cur0 = e0 + off; off += c0;
        int node1 = node + 1;
        if (node1 < NN) {
            rowStart[node1] = e0 + off;
            float di = rsqrtf((float)c1 + 1.0f);
            dinv[node1] = di;
            p1[node1] = x[node1] * di;
        }
        int cur1 = e0 + off; off += c1;
        cnt[k0] = cur0;
        cnt[k0 + 1] = cur1;
    }
    if (b == NBUCK - 1 && t == 0) rowStart[NN] = e1;
    __syncthreads();
    // phase 2: scatter (write amp ~6.6x is structural; see R12-R18 attempts)
    for (i = e0 + t; i + 3 * 1024 < e1; i += 4 * 1024) {
        int ea = bucketbuf[i];
        int eb = bucketbuf[i + 1024];
        int ec = bucketbuf[i + 2048];
        int ed = bucketbuf[i + 3072];
        int la = ea & 2047, sa = ea >> 11;
        int lb = eb & 2047, sb = eb >> 11;
        int lc = ec & 2047, sc = ec >> 11;
        int ld = ed & 2047, sd = ed >> 11;
        int pa = atomicAdd(&cnt[la], 1);
        int pb = atomicAdd(&cnt[lb], 1);
        int pc = atomicAdd(&cnt[lc], 1);
        int pd = atomicAdd(&cnt[ld], 1);
        edgebuf[pa] = sa;
        edgebuf[pb] = sb;
        edgebuf[pc] = sc;
        edgebuf[pd] = sd;
    }
    for (; i < e1; i += 1024) {
        int e = bucketbuf[i];
        int pos = atomicAdd(&cnt[e & 2047], 1);
        edgebuf[pos] = e >> 11;
    }
}

// ---- layer 1: per-node register gather of p1 (f32), ILP-8 -> p2h (f16x4) ----
__global__ __launch_bounds__(256) void agg1_kernel(const int* __restrict__ rowStart,
                                                   const int* __restrict__ edgebuf,
                                                   const float* __restrict__ p1,
                                                   const float* __restrict__ dinv,
                                                   const float* __restrict__ W1,
                                                   const float* __restrict__ b1,
                                                   const float* __restrict__ W2,
                                                   vhalf4* __restrict__ p2h) {
    int node = blockIdx.x * blockDim.x + threadIdx.x;
    if (node >= NN) return;
    int r0 = rowStart[node], r1 = rowStart[node + 1];
    float s0 = 0.f, s1 = 0.f, s2 = 0.f, s3 = 0.f;
    float s4 = 0.f, s5 = 0.f, s6 = 0.f, s7 = 0.f;
    int k = r0;
    for (; k + 8 <= r1; k += 8) {
        int a = edgebuf[k],     b = edgebuf[k + 1];
        int c = edgebuf[k + 2], d = edgebuf[k + 3];
        int e = edgebuf[k + 4], f = edgebuf[k + 5];
        int g = edgebuf[k + 6], h = edgebuf[k + 7];
        s0 += p1[a]; s1 += p1[b]; s2 += p1[c]; s3 += p1[d];
        s4 += p1[e]; s5 += p1[f]; s6 += p1[g]; s7 += p1[h];
    }
    for (; k < r1; ++k) s0 += p1[edgebuf[k]];
    float acc = ((s0 + s1) + (s2 + s3)) + ((s4 + s5) + (s6 + s7));
    float di = dinv[node];
    float t = di * (acc + p1[node]);   // norm-agg + self-loop
    float h1[4];
#pragma unroll
    for (int f2 = 0; f2 < 4; ++f2) h1[f2] = tanhf(t * W1[f2] + b1[f2]);
    vhalf4 g;
    g.x = (_Float16)(di * (h1[0]*W2[0] + h1[1]*W2[4] + h1[2]*W2[8]  + h1[3]*W2[12]));
    g.y = (_Float16)(di * (h1[0]*W2[1] + h1[1]*W2[5] + h1[2]*W2[9]  + h1[3]*W2[13]));
    g.z = (_Float16)(di * (h1[0]*W2[2] + h1[1]*W2[6] + h1[2]*W2[10] + h1[3]*W2[14]));
    g.w = (_Float16)(di * (h1[0]*W2[3] + h1[1]*W2[7] + h1[2]*W2[11] + h1[3]*W2[15]));
    p2h[node] = g;
}

// ---- layer 2: per-node register gather of p2h (f16x4, 4MB table), ILP-8 ----
__global__ __launch_bounds__(256) void agg2_kernel(const int* __restrict__ rowStart,
                                                   const int* __restrict__ edgebuf,
                                                   const vhalf4* __restrict__ p2h,
                                                   const float* __restrict__ dinv,
                                                   const float* __restrict__ b2,
                                                   const float* __restrict__ W3,
                                                   vhalf2* __restrict__ p3h) {
    int node = blockIdx.x * blockDim.x + threadIdx.x;
    if (node >= NN) return;
    int r0 = rowStart[node], r1 = rowStart[node + 1];
    vfloat4 sA = {0.f, 0.f, 0.f, 0.f};
    vfloat4 sB = {0.f, 0.f, 0.f, 0.f};
    vfloat4 sC = {0.f, 0.f, 0.f, 0.f};
    vfloat4 sD = {0.f, 0.f, 0.f, 0.f};
    int k = r0;
    for (; k + 8 <= r1; k += 8) {
        int a = edgebuf[k],     b = edgebuf[k + 1];
        int c = edgebuf[k + 2], d = edgebuf[k + 3];
        int e = edgebuf[k + 4], f = edgebuf[k + 5];
        int g = edgebuf[k + 6], h = edgebuf[k + 7];
        vhalf4 qa = p2h[a], qb = p2h[b], qc = p2h[c], qd = p2h[d];
        vhalf4 qe = p2h[e], qf = p2h[f], qg = p2h[g], qh = p2h[h];
        sA.x += (float)qa.x + (float)qb.x; sB.x += (float)qc.x + (float)qd.x;
        sA.y += (float)qa.y + (float)qb.y; sB.y += (float)qc.y + (float)qd.y;
        sA.z += (float)qa.z + (float)qb.z; sB.z += (float)qc.z + (float)qd.z;
        sA.w += (float)qa.w + (float)qb.w; sB.w += (float)qc.w + (float)qd.w;
        sC.x += (float)qe.x + (float)qf.x; sD.x += (float)qg.x + (float)qh.x;
        sC.y += (float)qe.y + (float)qf.y; sD.y += (float)qg.y + (float)qh.y;
        sC.z += (float)qe.z + (float)qf.z; sD.z += (float)qg.z + (float)qh.z;
        sC.w += (float)qe.w + (float)qf.w; sD.w += (float)qg.w + (float)qh.w;
    }
    for (; k < r1; ++k) {
        vhalf4 q = p2h[edgebuf[k]];
        sA.x += (float)q.x; sA.y += (float)q.y; sA.z += (float)q.z; sA.w += (float)q.w;
    }
    float di = dinv[node];
    vhalf4 pw = p2h[node];
    float h2[4];
    h2[0] = tanhf(di * (sA.x + sB.x + sC.x + sD.x + (float)pw.x) + b2[0]);
    h2[1] = tanhf(di * (sA.y + sB.y + sC.y + sD.y + (float)pw.y) + b2[1]);
    h2[2] = tanhf(di * (sA.z + sB.z + sC.z + sD.z + (float)pw.z) + b2[2]);
    h2[3] = tanhf(di * (sA.w + sB.w + sC.w + sD.w + (float)pw.w) + b2[3]);
    vhalf2 o;
    o.x = (_Float16)(di * (h2[0]*W3[0] + h2[1]*W3[2] + h2[2]*W3[4] + h2[3]*W3[6]));
    o.y = (_Float16)(di * (h2[0]*W3[1] + h2[1]*W3[3] + h2[2]*W3[5] + h2[3]*W3[7]));
    p3h[node] = o;
}

// ---- layer 3: per-node register gather of p3h (f16x2, 2MB table), ILP-8 ----
__global__ __launch_bounds__(256) void agg3_kernel(const int* __restrict__ rowStart,
                                                   const int* __restrict__ edgebuf,
                                                   const vhalf2* __restrict__ p3h,
                                                   const float* __restrict__ dinv,
                                                   const float* __restrict__ b3,
                                                   const float* __restrict__ Wc,
                                                   const float* __restrict__ bc,
                                                   float* __restrict__ out) {
    int node = blockIdx.x * blockDim.x + threadIdx.x;
    if (node >= NN) return;
    int r0 = rowStart[node], r1 = rowStart[node + 1];
    float ax = 0.f, ay = 0.f, bx = 0.f, by = 0.f;
    float cx = 0.f, cy = 0.f, dx = 0.f, dy = 0.f;
    int k = r0;
    for (; k + 8 <= r1; k += 8) {
        int a = edgebuf[k],     b = edgebuf[k + 1];
        int c = edgebuf[k + 2], d = edgebuf[k + 3];
        int e = edgebuf[k + 4], f = edgebuf[k + 5];
        int g = edgebuf[k + 6], h = edgebuf[k + 7];
        vhalf2 qa = p3h[a], qb = p3h[b], qc = p3h[c], qd = p3h[d];
        vhalf2 qe = p3h[e], qf = p3h[f], qg = p3h[g], qh = p3h[h];
        ax += (float)qa.x + (float)qb.x; bx += (float)qc.x + (float)qd.x;
        ay += (float)qa.y + (float)qb.y; by += (float)qc.y + (float)qd.y;
        cx += (float)qe.x + (float)qf.x; dx += (float)qg.x + (float)qh.x;
        cy += (float)qe.y + (float)qf.y; dy += (float)qg.y + (float)qh.y;
    }
    for (; k < r1; ++k) {
        vhalf2 q = p3h[edgebuf[k]];
        ax += (float)q.x; ay += (float)q.y;
    }
    float di = dinv[node];
    vhalf2 pw = p3h[node];
    float h0 = tanhf(di * (ax + bx + cx + dx + (float)pw.x) + b3[0]);
    float h1 = tanhf(di * (ay + by + cy + dy + (float)pw.y) + b3[1]);
    __builtin_nontemporal_store(h0 * Wc[0] + h1 * Wc[1] + bc[0], out + node);
    vfloat2 hh; hh.x = h0; hh.y = h1;
    __builtin_nontemporal_store(hh, (vfloat2*)(out + NN) + node);
}

// ============================ launch ============================

extern "C" void kernel_launch(void* const* d_in, const int* in_sizes, int n_in,
                              void* d_out, int out_size, void* d_ws, size_t ws_size,
                              hipStream_t stream) {
    const float* x   = (const float*)d_in[0];
    const int*   ei  = (const int*)d_in[1];
    const float* W1  = (const float*)d_in[2];
    const float* b1  = (const float*)d_in[3];
    const float* W2  = (const float*)d_in[4];
    const float* b2  = (const float*)d_in[5];
    const float* W3  = (const float*)d_in[6];
    const float* b3  = (const float*)d_in[7];
    const float* Wc  = (const float*)d_in[8];
    const float* bc  = (const float*)d_in[9];
    float* out = (float*)d_out;
    float* ws  = (float*)d_ws;

    const int* src = ei;
    const int* dst = ei + NE;

    float*  dinv      = ws;
    float*  p1        = ws + (size_t)NN;
    vhalf4* p2h       = (vhalf4*)(ws + 2ull * NN);
    vhalf2* p3h       = (vhalf2*)(ws + 4ull * NN);
    int*    rowStart  = (int*)(ws + 5ull * NN);
    int*    wgHist    = (int*)(ws + 6ull * NN + 1);
    int*    bktTotal  = wgHist + (size_t)NWGA * NBUCK;
    int*    bktStart  = bktTotal + NBUCK;
    int*    bucketbuf = bktStart + NBUCK + 1;
    int*    edgebuf   = bucketbuf + (size_t)NE;

    const int aggGrid = (NN + 255) / 256;            // 1954

    hipLaunchKernelGGL(hist_kernel, dim3(NWGA), dim3(512), 0, stream, dst, wgHist);
    hipLaunchKernelGGL(scanbins_kernel, dim3(NBUCK), dim3(256), 0, stream,
                       wgHist, bktTotal);
    hipLaunchKernelGGL(scantotal_kernel, dim3(1), dim3(256), 0, stream,
                       bktTotal, bktStart);
    hipLaunchKernelGGL(reorder_kernel, dim3(NWGA), dim3(512), 0, stream,
                       src, dst, wgHist, bktStart, bucketbuf);
    hipLaunchKernelGGL(csr3_kernel, dim3(NBUCK), dim3(1024), 0, stream,
                       bktStart, bucketbuf, x, dinv, p1, rowStart, edgebuf);
    hipLaunchKernelGGL(agg1_kernel, dim3(aggGrid), dim3(256), 0, stream,
                       rowStart, edgebuf, p1, dinv, W1, b1, W2, p2h);
    hipLaunchKernelGGL(agg2_kernel, dim3(aggGrid), dim3(256), 0, stream,
                       rowStart, edgebuf, p2h, dinv, b2, W3, p3h);
    hipLaunchKernelGGL(agg3_kernel, dim3(aggGrid), dim3(256), 0, stream,
                       rowStart, edgebuf, p3h, dinv, b3, Wc, bc, out);
}